// Round 1
// baseline (455.233 us; speedup 1.0000x reference)
//
#include <hip/hip_runtime.h>

#define S 2048
#define B 2
#define H 1024
#define NH 16
#define HD 64
#define THREE_H 3072
#define ROWS (S*B)   // 4096

// ---------------------------------------------------------------------------
// K1: qkv[r][c] = sum_k hidden[r][k] * W[c][k] + bias[c]
//     A: [4096 x 1024] row-major, W: [3072 x 1024] row-major (NT gemm)
//     128x128 tile, BK=32, 256 threads, 8x8 microtile
// ---------------------------------------------------------------------------
__global__ __launch_bounds__(256) void qkv_gemm(const float* __restrict__ A,
                                                const float* __restrict__ W,
                                                const float* __restrict__ bias,
                                                float* __restrict__ C) {
    __shared__ __align__(16) float As[32][136];  // [k][m], row pad 136 (16B-aligned rows)
    __shared__ __align__(16) float Bs[32][136];  // [k][n]
    const int tid = threadIdx.x;
    const int tx = tid & 15;        // 0..15 -> n
    const int ty = tid >> 4;        // 0..15 -> m
    const int row0 = blockIdx.x * 128;
    const int col0 = blockIdx.y * 128;

    float acc[8][8];
#pragma unroll
    for (int i = 0; i < 8; ++i)
#pragma unroll
        for (int j = 0; j < 8; ++j) acc[i][j] = 0.f;

    for (int k0 = 0; k0 < H; k0 += 32) {
        // stage A,W tiles: 128 rows x 32 k each = 1024 float4 per tile
#pragma unroll
        for (int p = 0; p < 4; ++p) {
            int idx = p * 256 + tid;       // 0..1023
            int r   = idx >> 3;            // 0..127
            int kq  = idx & 7;             // float4 within 32 k
            float4 av = *reinterpret_cast<const float4*>(&A[(size_t)(row0 + r) * H + k0 + kq * 4]);
            As[kq * 4 + 0][r] = av.x; As[kq * 4 + 1][r] = av.y;
            As[kq * 4 + 2][r] = av.z; As[kq * 4 + 3][r] = av.w;
            float4 wv = *reinterpret_cast<const float4*>(&W[(size_t)(col0 + r) * H + k0 + kq * 4]);
            Bs[kq * 4 + 0][r] = wv.x; Bs[kq * 4 + 1][r] = wv.y;
            Bs[kq * 4 + 2][r] = wv.z; Bs[kq * 4 + 3][r] = wv.w;
        }
        __syncthreads();

        for (int kk = 0; kk < 32; ++kk) {
            float4 alo = *reinterpret_cast<const float4*>(&As[kk][ty * 8]);
            float4 ahi = *reinterpret_cast<const float4*>(&As[kk][ty * 8 + 4]);
            float4 blo = *reinterpret_cast<const float4*>(&Bs[kk][tx * 8]);
            float4 bhi = *reinterpret_cast<const float4*>(&Bs[kk][tx * 8 + 4]);
            float av[8] = {alo.x, alo.y, alo.z, alo.w, ahi.x, ahi.y, ahi.z, ahi.w};
            float bv[8] = {blo.x, blo.y, blo.z, blo.w, bhi.x, bhi.y, bhi.z, bhi.w};
#pragma unroll
            for (int i = 0; i < 8; ++i)
#pragma unroll
                for (int j = 0; j < 8; ++j) acc[i][j] += av[i] * bv[j];
        }
        __syncthreads();
    }

#pragma unroll
    for (int i = 0; i < 8; ++i) {
        int r = row0 + ty * 8 + i;
#pragma unroll
        for (int j = 0; j < 8; ++j) {
            int c = col0 + tx * 8 + j;
            C[(size_t)r * THREE_H + c] = acc[i][j] + bias[c];
        }
    }
}

// ---------------------------------------------------------------------------
// V-suffix sum in 3 phases. col = (b*NH+h)*HD + d, 2048 cols; 32 chunks of 64 t.
// ---------------------------------------------------------------------------
__global__ void vsuf_chunksum(const float* __restrict__ qkv, float* __restrict__ csum) {
    int idx = blockIdx.x * 256 + threadIdx.x;   // 0..65535 = chunk*2048 + col
    int col = idx & 2047;
    int chunk = idx >> 11;
    int d = col & 63, h = (col >> 6) & 15, b = col >> 10;
    float s = 0.f;
    int t0 = chunk * 64;
    for (int t = t0; t < t0 + 64; ++t)
        s += qkv[(size_t)(t * B + b) * THREE_H + h * 192 + 128 + d];
    csum[idx] = s;
}

__global__ void vsuf_tail(const float* __restrict__ csum, float* __restrict__ tail) {
    int col = blockIdx.x * 256 + threadIdx.x;   // 0..2047
    float acc = 0.f;
    for (int c = 31; c >= 0; --c) {
        tail[c * 2048 + col] = acc;
        acc += csum[c * 2048 + col];
    }
}

__global__ void vsuf_final(const float* __restrict__ qkv, const float* __restrict__ tail,
                           float* __restrict__ vsuf) {
    int idx = blockIdx.x * 256 + threadIdx.x;   // chunk*2048 + col
    int col = idx & 2047;
    int chunk = idx >> 11;
    int d = col & 63, h = (col >> 6) & 15, b = col >> 10;
    int bh = b * NH + h;
    float acc = tail[chunk * 2048 + col];
    for (int t = chunk * 64 + 63; t >= chunk * 64; --t) {
        acc += qkv[(size_t)(t * B + b) * THREE_H + h * 192 + 128 + d];
        vsuf[((size_t)bh * S + t) * HD + d] = acc;
    }
}

// ---------------------------------------------------------------------------
// K3: Mpart[chunk][bh][i][j] = sum_{t in chunk(256)} K[t][i] * Vsuf[t][j]
//     per block: one (bh, chunk); 256 threads, 4x4 microtile over 64x64 out
// ---------------------------------------------------------------------------
__global__ __launch_bounds__(256) void kvm_partial(const float* __restrict__ qkv,
                                                   const float* __restrict__ vsuf,
                                                   float* __restrict__ Mpart) {
    __shared__ __align__(16) float Ks[64][72];
    __shared__ __align__(16) float Vs[64][72];
    const int bh = blockIdx.x;      // 0..31
    const int chunk = blockIdx.y;   // 0..7
    const int b = bh / NH, h = bh % NH;
    const int tid = threadIdx.x;
    const int tx = tid & 15, ty = tid >> 4;

    float acc[4][4] = {{0.f}};
    for (int t0 = chunk * 256; t0 < chunk * 256 + 256; t0 += 64) {
#pragma unroll
        for (int p = 0; p < 4; ++p) {
            int idx = p * 256 + tid;    // 0..1023
            int tt = idx >> 4;          // 0..63
            int i4 = idx & 15;
            float4 kv = *reinterpret_cast<const float4*>(
                &qkv[(size_t)((t0 + tt) * B + b) * THREE_H + h * 192 + 64 + i4 * 4]);
            *reinterpret_cast<float4*>(&Ks[tt][i4 * 4]) = kv;
            float4 vv = *reinterpret_cast<const float4*>(
                &vsuf[((size_t)bh * S + t0 + tt) * HD + i4 * 4]);
            *reinterpret_cast<float4*>(&Vs[tt][i4 * 4]) = vv;
        }
        __syncthreads();
        for (int kk = 0; kk < 64; ++kk) {
            float4 a = *reinterpret_cast<const float4*>(&Ks[kk][ty * 4]);
            float4 v = *reinterpret_cast<const float4*>(&Vs[kk][tx * 4]);
            float av[4] = {a.x, a.y, a.z, a.w};
            float bv[4] = {v.x, v.y, v.z, v.w};
#pragma unroll
            for (int i = 0; i < 4; ++i)
#pragma unroll
                for (int j = 0; j < 4; ++j) acc[i][j] += av[i] * bv[j];
        }
        __syncthreads();
    }
#pragma unroll
    for (int i = 0; i < 4; ++i)
#pragma unroll
        for (int j = 0; j < 4; ++j)
            Mpart[(size_t)(chunk * 32 + bh) * 4096 + (ty * 4 + i) * 64 + tx * 4 + j] = acc[i][j];
}

__global__ void reduce_m(const float* __restrict__ Mpart, float* __restrict__ M) {
    int idx = blockIdx.x * 256 + threadIdx.x;   // 0..131071 = bh*4096 + e
    float acc = 0.f;
#pragma unroll
    for (int c = 0; c < 8; ++c) acc += Mpart[(size_t)c * 131072 + idx];
    M[idx] = acc;
}

// ---------------------------------------------------------------------------
// K4: out[r][h*64+d] = scale * sum_i q[r][h][i] * M[bh][i][d]
// ---------------------------------------------------------------------------
__global__ __launch_bounds__(256) void qm_ctx(const float* __restrict__ qkv,
                                              const float* __restrict__ M,
                                              float* __restrict__ out) {
    __shared__ float qs[NH][HD];
    const int r = blockIdx.x;        // s*B + b
    const int b = r % B;
    const int tid = threadIdx.x;
    for (int idx = tid; idx < NH * HD; idx += 256) {
        int h = idx >> 6, i = idx & 63;
        qs[h][i] = qkv[(size_t)r * THREE_H + h * 192 + i];
    }
    __syncthreads();
    const float scale = 0.125f * 0.02209708691207961f;  // HD^-0.5 * S^-0.5
    const int ty = tid >> 6, d = tid & 63;
#pragma unroll
    for (int hh = 0; hh < 4; ++hh) {
        int h = hh * 4 + ty;
        const float* Mp = &M[(size_t)(b * NH + h) * 4096];
        float acc = 0.f;
#pragma unroll
        for (int i = 0; i < 64; ++i) acc += qs[h][i] * Mp[i * 64 + d];
        out[(size_t)r * H + h * 64 + d] = acc * scale;
    }
}

// ---------------------------------------------------------------------------
extern "C" void kernel_launch(void* const* d_in, const int* in_sizes, int n_in,
                              void* d_out, int out_size, void* d_ws, size_t ws_size,
                              hipStream_t stream) {
    const float* hidden = (const float*)d_in[0];
    const float* W      = (const float*)d_in[1];
    const float* bias   = (const float*)d_in[2];
    float* out = (float*)d_out;

    float* qkv   = (float*)d_ws;                         // 12,582,912 f
    float* vsuf  = qkv   + (size_t)ROWS * THREE_H;       //  4,194,304 f
    float* Mpart = vsuf  + (size_t)B * NH * S * HD;      //  1,048,576 f
    float* M     = Mpart + (size_t)8 * B * NH * HD * HD; //    131,072 f
    float* csum  = M     + (size_t)B * NH * HD * HD;     //     65,536 f
    float* tail  = csum  + 65536;                        //     65,536 f
    // total ~72.4 MB of d_ws

    qkv_gemm<<<dim3(ROWS / 128, THREE_H / 128), 256, 0, stream>>>(hidden, W, bias, qkv);
    vsuf_chunksum<<<256, 256, 0, stream>>>(qkv, csum);
    vsuf_tail<<<8, 256, 0, stream>>>(csum, tail);
    vsuf_final<<<256, 256, 0, stream>>>(qkv, tail, vsuf);
    kvm_partial<<<dim3(32, 8), 256, 0, stream>>>(qkv, vsuf, Mpart);
    reduce_m<<<512, 256, 0, stream>>>(Mpart, M);
    qm_ctx<<<ROWS, 256, 0, stream>>>(qkv, M, out);
}

// Round 2
// 132.794 us; speedup vs baseline: 3.4281x; 3.4281x over previous
//
#include <hip/hip_runtime.h>

#define S 2048
#define B 2
#define H 1024
#define NH 16
#define HD 64
#define THREE_H 3072
#define ROWS (S*B)   // 4096

typedef __attribute__((ext_vector_type(8))) short short8;
typedef __attribute__((ext_vector_type(4))) float f32x4;
typedef const __attribute__((address_space(1))) unsigned int* gptr_t;
typedef __attribute__((address_space(3))) unsigned int* lptr_t;

__device__ __forceinline__ ushort f2bf(float f) {
    union { float f; unsigned u; } v; v.f = f;
    unsigned r = v.u + 0x7fffu + ((v.u >> 16) & 1u);
    return (ushort)(r >> 16);
}

// ---------------------------------------------------------------------------
// Cast f32 -> bf16, 8 elements/thread
// ---------------------------------------------------------------------------
__global__ void cast_f32_bf16(const float* __restrict__ src, ushort* __restrict__ dst, int n8) {
    int i = blockIdx.x * 256 + threadIdx.x;
    if (i >= n8) return;
    const float4* s4 = (const float4*)src;
    float4 a = s4[2 * i], b = s4[2 * i + 1];
    short8 o;
    o[0] = f2bf(a.x); o[1] = f2bf(a.y); o[2] = f2bf(a.z); o[3] = f2bf(a.w);
    o[4] = f2bf(b.x); o[5] = f2bf(b.y); o[6] = f2bf(b.z); o[7] = f2bf(b.w);
    *(short8*)(dst + 8 * (size_t)i) = o;
}

// ---------------------------------------------------------------------------
// K1: bf16 MFMA GEMM (m97 structure). C[r][c] = sum_k A[r][k]*W[c][k] + bias[c]
// 128x128 tile, BK=32, 256 threads (4 waves, 2x2 wave grid, 4x4 frags/wave)
// ---------------------------------------------------------------------------
__global__ __launch_bounds__(256) void qkv_gemm_mfma(const ushort* __restrict__ Abf,
                                                     const ushort* __restrict__ Wbf,
                                                     const float* __restrict__ bias,
                                                     float* __restrict__ C) {
    __shared__ ushort Abuf[128 * 32];
    __shared__ ushort Bbuf[128 * 32];
    const int tid = threadIdx.x;
    const int wave = tid >> 6, lane = tid & 63;
    const int wr = wave >> 1, wc = wave & 1;
    const int row0 = blockIdx.x * 128;
    const int col0 = blockIdx.y * 128;

    f32x4 acc[4][4] = {};

    const int lrow = lane >> 2;        // 0..15 within 16-row chunk
    const int lk   = (lane & 3) * 8;   // 0,8,16,24

    for (int k0 = 0; k0 < H; k0 += 32) {
#pragma unroll
        for (int p = 0; p < 2; ++p) {
            int c = wave * 2 + p;          // 0..7 -> rows [c*16, c*16+16)
            int row = c * 16 + lrow;
            __builtin_amdgcn_global_load_lds(
                (gptr_t)&Abf[(size_t)(row0 + row) * H + k0 + lk],
                (lptr_t)&Abuf[c * 512 + lane * 8], 16, 0, 0);
            __builtin_amdgcn_global_load_lds(
                (gptr_t)&Wbf[(size_t)(col0 + row) * H + k0 + lk],
                (lptr_t)&Bbuf[c * 512 + lane * 8], 16, 0, 0);
        }
        __syncthreads();

        short8 af[4], bfr[4];
#pragma unroll
        for (int m = 0; m < 4; ++m) {
            int ar = wr * 64 + m * 16 + (lane & 15);
            af[m] = *(const short8*)&Abuf[ar * 32 + (lane >> 4) * 8];
            int br = wc * 64 + m * 16 + (lane & 15);
            bfr[m] = *(const short8*)&Bbuf[br * 32 + (lane >> 4) * 8];
        }
#pragma unroll
        for (int m = 0; m < 4; ++m)
#pragma unroll
            for (int n = 0; n < 4; ++n)
                acc[m][n] = __builtin_amdgcn_mfma_f32_16x16x32_bf16(af[m], bfr[n], acc[m][n], 0, 0, 0);
        __syncthreads();
    }

#pragma unroll
    for (int n = 0; n < 4; ++n) {
        int colg = col0 + wc * 64 + n * 16 + (lane & 15);
        float bv = bias[colg];
#pragma unroll
        for (int m = 0; m < 4; ++m) {
            int rowb = row0 + wr * 64 + m * 16 + (lane >> 4) * 4;
#pragma unroll
            for (int j = 0; j < 4; ++j)
                C[(size_t)(rowb + j) * THREE_H + colg] = acc[m][n][j] + bv;
        }
    }
}

// ---------------------------------------------------------------------------
// V-suffix sum in 3 phases. col = (b*NH+h)*HD + d, 2048 cols; 32 chunks of 64 t.
// ---------------------------------------------------------------------------
__global__ void vsuf_chunksum(const float* __restrict__ qkv, float* __restrict__ csum) {
    int idx = blockIdx.x * 256 + threadIdx.x;   // chunk*2048 + col
    int col = idx & 2047;
    int chunk = idx >> 11;
    int d = col & 63, h = (col >> 6) & 15, b = col >> 10;
    float s = 0.f;
    int t0 = chunk * 64;
    for (int t = t0; t < t0 + 64; ++t)
        s += qkv[(size_t)(t * B + b) * THREE_H + h * 192 + 128 + d];
    csum[idx] = s;
}

__global__ void vsuf_tail(const float* __restrict__ csum, float* __restrict__ tail) {
    int col = blockIdx.x * 256 + threadIdx.x;   // 0..2047
    float acc = 0.f;
    for (int c = 31; c >= 0; --c) {
        tail[c * 2048 + col] = acc;
        acc += csum[c * 2048 + col];
    }
}

__global__ void vsuf_final(const float* __restrict__ qkv, const float* __restrict__ tail,
                           float* __restrict__ vsuf) {
    int idx = blockIdx.x * 256 + threadIdx.x;   // chunk*2048 + col
    int col = idx & 2047;
    int chunk = idx >> 11;
    int d = col & 63, h = (col >> 6) & 15, b = col >> 10;
    int bh = b * NH + h;
    float acc = tail[chunk * 2048 + col];
    for (int t = chunk * 64 + 63; t >= chunk * 64; --t) {
        acc += qkv[(size_t)(t * B + b) * THREE_H + h * 192 + 128 + d];
        vsuf[((size_t)bh * S + t) * HD + d] = acc;
    }
}

// ---------------------------------------------------------------------------
// K3: Mpart[chunk][bh][i][j] = sum_{t in chunk(256)} K[t][i] * Vsuf[t][j]
// ---------------------------------------------------------------------------
__global__ __launch_bounds__(256) void kvm_partial(const float* __restrict__ qkv,
                                                   const float* __restrict__ vsuf,
                                                   float* __restrict__ Mpart) {
    __shared__ __align__(16) float Ks[64][72];
    __shared__ __align__(16) float Vs[64][72];
    const int bh = blockIdx.x;      // 0..31
    const int chunk = blockIdx.y;   // 0..7
    const int b = bh / NH, h = bh % NH;
    const int tid = threadIdx.x;
    const int tx = tid & 15, ty = tid >> 4;

    float acc[4][4] = {{0.f}};
    for (int t0 = chunk * 256; t0 < chunk * 256 + 256; t0 += 64) {
#pragma unroll
        for (int p = 0; p < 4; ++p) {
            int idx = p * 256 + tid;
            int tt = idx >> 4;
            int i4 = idx & 15;
            float4 kv = *reinterpret_cast<const float4*>(
                &qkv[(size_t)((t0 + tt) * B + b) * THREE_H + h * 192 + 64 + i4 * 4]);
            *reinterpret_cast<float4*>(&Ks[tt][i4 * 4]) = kv;
            float4 vv = *reinterpret_cast<const float4*>(
                &vsuf[((size_t)bh * S + t0 + tt) * HD + i4 * 4]);
            *reinterpret_cast<float4*>(&Vs[tt][i4 * 4]) = vv;
        }
        __syncthreads();
        for (int kk = 0; kk < 64; ++kk) {
            float4 a = *reinterpret_cast<const float4*>(&Ks[kk][ty * 4]);
            float4 v = *reinterpret_cast<const float4*>(&Vs[kk][tx * 4]);
            float av[4] = {a.x, a.y, a.z, a.w};
            float bv[4] = {v.x, v.y, v.z, v.w};
#pragma unroll
            for (int i = 0; i < 4; ++i)
#pragma unroll
                for (int j = 0; j < 4; ++j) acc[i][j] += av[i] * bv[j];
        }
        __syncthreads();
    }
#pragma unroll
    for (int i = 0; i < 4; ++i)
#pragma unroll
        for (int j = 0; j < 4; ++j)
            Mpart[(size_t)(chunk * 32 + bh) * 4096 + (ty * 4 + i) * 64 + tx * 4 + j] = acc[i][j];
}

__global__ void reduce_m(const float* __restrict__ Mpart, float* __restrict__ M) {
    int idx = blockIdx.x * 256 + threadIdx.x;   // bh*4096 + e
    float acc = 0.f;
#pragma unroll
    for (int c = 0; c < 8; ++c) acc += Mpart[(size_t)c * 131072 + idx];
    M[idx] = acc;
}

// ---------------------------------------------------------------------------
// K4: out[s][b][h*64+d] = scale * sum_i q[s][b][h][i] * M[bh][i][d]
// grid (32 bh, 16 s-chunks), M staged in LDS once per block
// ---------------------------------------------------------------------------
__global__ __launch_bounds__(256) void qm_ctx(const float* __restrict__ qkv,
                                              const float* __restrict__ M,
                                              float* __restrict__ out) {
    __shared__ float Ms[64][64];
    const int bh = blockIdx.x;
    const int b = bh >> 4, h = bh & 15;
    const int tid = threadIdx.x;
    for (int e = tid; e < 4096; e += 256)
        Ms[e >> 6][e & 63] = M[(size_t)bh * 4096 + e];
    __syncthreads();
    const float scale = 0.125f * 0.02209708691207961f;  // HD^-0.5 * S^-0.5
    const int wave = tid >> 6, lane = tid & 63;
    const int s0 = blockIdx.y * 128;
    for (int s = s0 + wave; s < s0 + 128; s += 4) {
        const float* qp = &qkv[(size_t)(s * B + b) * THREE_H + h * 192];
        float acc = 0.f;
#pragma unroll
        for (int i = 0; i < 64; ++i) acc += qp[i] * Ms[i][lane];
        out[(size_t)(s * B + b) * H + h * 64 + lane] = acc * scale;
    }
}

// ---------------------------------------------------------------------------
extern "C" void kernel_launch(void* const* d_in, const int* in_sizes, int n_in,
                              void* d_out, int out_size, void* d_ws, size_t ws_size,
                              hipStream_t stream) {
    const float* hidden = (const float*)d_in[0];
    const float* W      = (const float*)d_in[1];
    const float* bias   = (const float*)d_in[2];
    float* out = (float*)d_out;

    float* qkv   = (float*)d_ws;                         // 12,582,912 f
    float* vsuf  = qkv   + (size_t)ROWS * THREE_H;       //  4,194,304 f
    float* Mpart = vsuf  + (size_t)B * NH * S * HD;      //  1,048,576 f
    float* M     = Mpart + (size_t)8 * B * NH * HD * HD; //    131,072 f
    float* csum  = M     + (size_t)B * NH * HD * HD;     //     65,536 f
    float* tail  = csum  + 65536;                        //     65,536 f

    // bf16 inputs alias the vsuf region (dead until vsuf_final writes it,
    // and the gemm that consumes them completes before that)
    ushort* Ahb = (ushort*)vsuf;                         // 4,194,304 bf16 (8MB)
    ushort* Whb = Ahb + (size_t)ROWS * H;                // 3,145,728 bf16 (6MB)

    cast_f32_bf16<<<(ROWS * H / 8 + 255) / 256, 256, 0, stream>>>(hidden, Ahb, ROWS * H / 8);
    cast_f32_bf16<<<(THREE_H * H / 8 + 255) / 256, 256, 0, stream>>>(W, Whb, THREE_H * H / 8);

    qkv_gemm_mfma<<<dim3(ROWS / 128, THREE_H / 128), 256, 0, stream>>>(Ahb, Whb, bias, qkv);

    vsuf_chunksum<<<256, 256, 0, stream>>>(qkv, csum);
    vsuf_tail<<<8, 256, 0, stream>>>(csum, tail);
    vsuf_final<<<256, 256, 0, stream>>>(qkv, tail, vsuf);
    kvm_partial<<<dim3(32, 8), 256, 0, stream>>>(qkv, vsuf, Mpart);
    reduce_m<<<512, 256, 0, stream>>>(Mpart, M);
    qm_ctx<<<dim3(32, 16), 256, 0, stream>>>(qkv, M, out);
}

// Round 3
// 117.300 us; speedup vs baseline: 3.8809x; 1.1321x over previous
//
#include <hip/hip_runtime.h>

#define S 2048
#define B 2
#define H 1024
#define NH 16
#define HD 64
#define THREE_H 3072
#define ROWS (S*B)   // 4096

typedef __attribute__((ext_vector_type(8))) short short8;
typedef __attribute__((ext_vector_type(4))) float f32x4;
typedef const __attribute__((address_space(1))) unsigned int* gptr_t;
typedef __attribute__((address_space(3))) unsigned int* lptr_t;

#define N8_A (ROWS * H / 8)        // 524288
#define N8_W (THREE_H * H / 8)     // 393216

__device__ __forceinline__ ushort f2bf(float f) {
    union { float f; unsigned u; } v; v.f = f;
    unsigned r = v.u + 0x7fffu + ((v.u >> 16) & 1u);
    return (ushort)(r >> 16);
}

// ---------------------------------------------------------------------------
// Cast f32 -> bf16 for A and W in one launch
// ---------------------------------------------------------------------------
__global__ void cast_both(const float* __restrict__ A, const float* __restrict__ W,
                          ushort* __restrict__ Ab, ushort* __restrict__ Wb) {
    int i = blockIdx.x * 256 + threadIdx.x;
    const float4* s4;
    ushort* dst;
    if (i < N8_A) { s4 = (const float4*)A; dst = Ab; }
    else if (i < N8_A + N8_W) { s4 = (const float4*)W; dst = Wb; i -= N8_A; }
    else return;
    float4 a = s4[2 * i], b = s4[2 * i + 1];
    short8 o;
    o[0] = f2bf(a.x); o[1] = f2bf(a.y); o[2] = f2bf(a.z); o[3] = f2bf(a.w);
    o[4] = f2bf(b.x); o[5] = f2bf(b.y); o[6] = f2bf(b.z); o[7] = f2bf(b.w);
    *(short8*)(dst + 8 * (size_t)i) = o;
}

// ---------------------------------------------------------------------------
// K1: bf16 MFMA GEMM (m97 structure). C[r][c] = sum_k A[r][k]*W[c][k] + bias[c]
// ---------------------------------------------------------------------------
__global__ __launch_bounds__(256) void qkv_gemm_mfma(const ushort* __restrict__ Abf,
                                                     const ushort* __restrict__ Wbf,
                                                     const float* __restrict__ bias,
                                                     float* __restrict__ C) {
    __shared__ ushort Abuf[128 * 32];
    __shared__ ushort Bbuf[128 * 32];
    const int tid = threadIdx.x;
    const int wave = tid >> 6, lane = tid & 63;
    const int wr = wave >> 1, wc = wave & 1;
    const int row0 = blockIdx.x * 128;
    const int col0 = blockIdx.y * 128;

    f32x4 acc[4][4] = {};

    const int lrow = lane >> 2;        // 0..15
    const int lk   = (lane & 3) * 8;   // 0,8,16,24

    for (int k0 = 0; k0 < H; k0 += 32) {
#pragma unroll
        for (int p = 0; p < 2; ++p) {
            int c = wave * 2 + p;
            int row = c * 16 + lrow;
            __builtin_amdgcn_global_load_lds(
                (gptr_t)&Abf[(size_t)(row0 + row) * H + k0 + lk],
                (lptr_t)&Abuf[c * 512 + lane * 8], 16, 0, 0);
            __builtin_amdgcn_global_load_lds(
                (gptr_t)&Wbf[(size_t)(col0 + row) * H + k0 + lk],
                (lptr_t)&Bbuf[c * 512 + lane * 8], 16, 0, 0);
        }
        __syncthreads();

        short8 af[4], bfr[4];
#pragma unroll
        for (int m = 0; m < 4; ++m) {
            int ar = wr * 64 + m * 16 + (lane & 15);
            af[m] = *(const short8*)&Abuf[ar * 32 + (lane >> 4) * 8];
            int br = wc * 64 + m * 16 + (lane & 15);
            bfr[m] = *(const short8*)&Bbuf[br * 32 + (lane >> 4) * 8];
        }
#pragma unroll
        for (int m = 0; m < 4; ++m)
#pragma unroll
            for (int n = 0; n < 4; ++n)
                acc[m][n] = __builtin_amdgcn_mfma_f32_16x16x32_bf16(af[m], bfr[n], acc[m][n], 0, 0, 0);
        __syncthreads();
    }

#pragma unroll
    for (int n = 0; n < 4; ++n) {
        int colg = col0 + wc * 64 + n * 16 + (lane & 15);
        float bv = bias[colg];
#pragma unroll
        for (int m = 0; m < 4; ++m) {
            int rowb = row0 + wr * 64 + m * 16 + (lane >> 4) * 4;
#pragma unroll
            for (int j = 0; j < 4; ++j)
                C[(size_t)(rowb + j) * THREE_H + colg] = acc[m][n][j] + bv;
        }
    }
}

// ---------------------------------------------------------------------------
// V-suffix scan: 64 chunks of 32 t. Phase 1: chunk sums. Phase 2 (fused):
// tail = sum of later chunk-sums (csum is L2-hot, 512KB) + in-chunk scan.
// ---------------------------------------------------------------------------
__global__ void vsuf_chunksum(const float* __restrict__ qkv, float* __restrict__ csum) {
    int idx = blockIdx.x * 256 + threadIdx.x;   // chunk*2048 + col, 131072 total
    int col = idx & 2047;
    int chunk = idx >> 11;                      // 0..63
    int d = col & 63, h = (col >> 6) & 15, b = col >> 10;
    float s = 0.f;
    int t0 = chunk * 32;
    for (int t = t0; t < t0 + 32; ++t)
        s += qkv[(size_t)(t * B + b) * THREE_H + h * 192 + 128 + d];
    csum[idx] = s;
}

__global__ void vsuf_final(const float* __restrict__ qkv, const float* __restrict__ csum,
                           float* __restrict__ vsuf) {
    int idx = blockIdx.x * 256 + threadIdx.x;   // chunk*2048 + col
    int col = idx & 2047;
    int chunk = idx >> 11;                      // 0..63
    int d = col & 63, h = (col >> 6) & 15, b = col >> 10;
    int bh = b * NH + h;
    float acc = 0.f;
    for (int c = chunk + 1; c < 64; ++c) acc += csum[c * 2048 + col];
    for (int t = chunk * 32 + 31; t >= chunk * 32; --t) {
        acc += qkv[(size_t)(t * B + b) * THREE_H + h * 192 + 128 + d];
        vsuf[((size_t)bh * S + t) * HD + d] = acc;
    }
}

// ---------------------------------------------------------------------------
// K3: Mpart[chunk][bh][i][j] = sum_{t in chunk(128)} K[t][i] * Vsuf[t][j]
// ---------------------------------------------------------------------------
__global__ __launch_bounds__(256) void kvm_partial(const float* __restrict__ qkv,
                                                   const float* __restrict__ vsuf,
                                                   float* __restrict__ Mpart) {
    __shared__ __align__(16) float Ks[64][72];
    __shared__ __align__(16) float Vs[64][72];
    const int bh = blockIdx.x;      // 0..31
    const int chunk = blockIdx.y;   // 0..15
    const int b = bh / NH, h = bh % NH;
    const int tid = threadIdx.x;
    const int tx = tid & 15, ty = tid >> 4;

    float acc[4][4] = {{0.f}};
    for (int t0 = chunk * 128; t0 < chunk * 128 + 128; t0 += 64) {
#pragma unroll
        for (int p = 0; p < 4; ++p) {
            int idx = p * 256 + tid;
            int tt = idx >> 4;
            int i4 = idx & 15;
            float4 kv = *reinterpret_cast<const float4*>(
                &qkv[(size_t)((t0 + tt) * B + b) * THREE_H + h * 192 + 64 + i4 * 4]);
            *reinterpret_cast<float4*>(&Ks[tt][i4 * 4]) = kv;
            float4 vv = *reinterpret_cast<const float4*>(
                &vsuf[((size_t)bh * S + t0 + tt) * HD + i4 * 4]);
            *reinterpret_cast<float4*>(&Vs[tt][i4 * 4]) = vv;
        }
        __syncthreads();
        for (int kk = 0; kk < 64; ++kk) {
            float4 a = *reinterpret_cast<const float4*>(&Ks[kk][ty * 4]);
            float4 v = *reinterpret_cast<const float4*>(&Vs[kk][tx * 4]);
            float av[4] = {a.x, a.y, a.z, a.w};
            float bv[4] = {v.x, v.y, v.z, v.w};
#pragma unroll
            for (int i = 0; i < 4; ++i)
#pragma unroll
                for (int j = 0; j < 4; ++j) acc[i][j] += av[i] * bv[j];
        }
        __syncthreads();
    }
#pragma unroll
    for (int i = 0; i < 4; ++i)
#pragma unroll
        for (int j = 0; j < 4; ++j)
            Mpart[(size_t)(chunk * 32 + bh) * 4096 + (ty * 4 + i) * 64 + tx * 4 + j] = acc[i][j];
}

__global__ void reduce_m(const float* __restrict__ Mpart, float* __restrict__ M) {
    int idx = blockIdx.x * 256 + threadIdx.x;   // bh*4096 + e
    float acc = 0.f;
#pragma unroll
    for (int c = 0; c < 16; ++c) acc += Mpart[(size_t)c * 131072 + idx];
    M[idx] = acc;
}

// ---------------------------------------------------------------------------
// K4: out[s][b][h*64+d] = scale * sum_i q[s][b][h][i] * M[bh][i][d]
// ---------------------------------------------------------------------------
__global__ __launch_bounds__(256) void qm_ctx(const float* __restrict__ qkv,
                                              const float* __restrict__ M,
                                              float* __restrict__ out) {
    __shared__ float Ms[64][64];
    const int bh = blockIdx.x;
    const int b = bh >> 4, h = bh & 15;
    const int tid = threadIdx.x;
    for (int e = tid; e < 4096; e += 256)
        Ms[e >> 6][e & 63] = M[(size_t)bh * 4096 + e];
    __syncthreads();
    const float scale = 0.125f * 0.02209708691207961f;  // HD^-0.5 * S^-0.5
    const int wave = tid >> 6, lane = tid & 63;
    const int s0 = blockIdx.y * 128;
    for (int s = s0 + wave; s < s0 + 128; s += 4) {
        const float* qp = &qkv[(size_t)(s * B + b) * THREE_H + h * 192];
        float acc = 0.f;
#pragma unroll
        for (int i = 0; i < 64; ++i) acc += qp[i] * Ms[i][lane];
        out[(size_t)(s * B + b) * H + h * 64 + lane] = acc * scale;
    }
}

// ---------------------------------------------------------------------------
extern "C" void kernel_launch(void* const* d_in, const int* in_sizes, int n_in,
                              void* d_out, int out_size, void* d_ws, size_t ws_size,
                              hipStream_t stream) {
    const float* hidden = (const float*)d_in[0];
    const float* W      = (const float*)d_in[1];
    const float* bias   = (const float*)d_in[2];
    float* out = (float*)d_out;

    float* qkv   = (float*)d_ws;                          // 12,582,912 f
    float* vsuf  = qkv   + (size_t)ROWS * THREE_H;        //  4,194,304 f
    float* Mpart = vsuf  + (size_t)B * NH * S * HD;       //  2,097,152 f (16 slices)
    float* M     = Mpart + (size_t)16 * B * NH * HD * HD; //    131,072 f
    float* csum  = M     + (size_t)B * NH * HD * HD;      //    131,072 f
    // total ~76.5 MB of d_ws (ws ~256 MB per fill-size evidence)

    // bf16 inputs alias the vsuf region (dead until vsuf_final writes it)
    ushort* Ahb = (ushort*)vsuf;                          // 8 MB
    ushort* Whb = Ahb + (size_t)ROWS * H;                 // 6 MB

    cast_both<<<(N8_A + N8_W + 255) / 256, 256, 0, stream>>>(hidden, W, Ahb, Whb);
    qkv_gemm_mfma<<<dim3(ROWS / 128, THREE_H / 128), 256, 0, stream>>>(Ahb, Whb, bias, qkv);
    vsuf_chunksum<<<512, 256, 0, stream>>>(qkv, csum);
    vsuf_final<<<512, 256, 0, stream>>>(qkv, csum, vsuf);
    kvm_partial<<<dim3(32, 16), 256, 0, stream>>>(qkv, vsuf, Mpart);
    reduce_m<<<512, 256, 0, stream>>>(Mpart, M);
    qm_ctx<<<dim3(32, 16), 256, 0, stream>>>(qkv, M, out);
}

// Round 4
// 86.160 us; speedup vs baseline: 5.2836x; 1.3614x over previous
//
#include <hip/hip_runtime.h>

#define S 2048
#define B 2
#define H 1024
#define NH 16
#define HD 64
#define THREE_H 3072
#define ROWS (S*B)   // 4096

typedef __attribute__((ext_vector_type(8))) short short8;
typedef __attribute__((ext_vector_type(4))) float f32x4;
typedef const __attribute__((address_space(1))) unsigned int* gptr_t;
typedef __attribute__((address_space(3))) unsigned int* lptr_t;

#define N8_A (ROWS * H / 8)        // 524288
#define N8_W (THREE_H * H / 8)     // 393216

__device__ __forceinline__ ushort f2bf(float f) {
    union { float f; unsigned u; } v; v.f = f;
    unsigned r = v.u + 0x7fffu + ((v.u >> 16) & 1u);
    return (ushort)(r >> 16);
}

// ---------------------------------------------------------------------------
// Cast f32 -> bf16 for A and W in one launch
// ---------------------------------------------------------------------------
__global__ void cast_both(const float* __restrict__ A, const float* __restrict__ W,
                          ushort* __restrict__ Ab, ushort* __restrict__ Wb) {
    int i = blockIdx.x * 256 + threadIdx.x;
    const float4* s4;
    ushort* dst;
    if (i < N8_A) { s4 = (const float4*)A; dst = Ab; }
    else if (i < N8_A + N8_W) { s4 = (const float4*)W; dst = Wb; i -= N8_A; }
    else return;
    float4 a = s4[2 * i], b = s4[2 * i + 1];
    short8 o;
    o[0] = f2bf(a.x); o[1] = f2bf(a.y); o[2] = f2bf(a.z); o[3] = f2bf(a.w);
    o[4] = f2bf(b.x); o[5] = f2bf(b.y); o[6] = f2bf(b.z); o[7] = f2bf(b.w);
    *(short8*)(dst + 8 * (size_t)i) = o;
}

// ---------------------------------------------------------------------------
// K1: bf16 MFMA GEMM. Epilogue scatters to Qb/Kb (bf16, [bh][s][d]) and
// Vf (f32, [bh][t][d]). sel/h/d are wave-uniform per n-subtile.
// ---------------------------------------------------------------------------
__global__ __launch_bounds__(256) void qkv_gemm_mfma(const ushort* __restrict__ Abf,
                                                     const ushort* __restrict__ Wbf,
                                                     const float* __restrict__ bias,
                                                     ushort* __restrict__ Qb,
                                                     ushort* __restrict__ Kb,
                                                     float* __restrict__ Vf) {
    __shared__ ushort Abuf[128 * 32];
    __shared__ ushort Bbuf[128 * 32];
    const int tid = threadIdx.x;
    const int wave = tid >> 6, lane = tid & 63;
    const int wr = wave >> 1, wc = wave & 1;
    const int row0 = blockIdx.x * 128;
    const int col0 = blockIdx.y * 128;

    f32x4 acc[4][4] = {};

    const int lrow = lane >> 2;        // 0..15
    const int lk   = (lane & 3) * 8;   // 0,8,16,24

    for (int k0 = 0; k0 < H; k0 += 32) {
#pragma unroll
        for (int p = 0; p < 2; ++p) {
            int c = wave * 2 + p;
            int row = c * 16 + lrow;
            __builtin_amdgcn_global_load_lds(
                (gptr_t)&Abf[(size_t)(row0 + row) * H + k0 + lk],
                (lptr_t)&Abuf[c * 512 + lane * 8], 16, 0, 0);
            __builtin_amdgcn_global_load_lds(
                (gptr_t)&Wbf[(size_t)(col0 + row) * H + k0 + lk],
                (lptr_t)&Bbuf[c * 512 + lane * 8], 16, 0, 0);
        }
        __syncthreads();

        short8 af[4], bfr[4];
#pragma unroll
        for (int m = 0; m < 4; ++m) {
            int ar = wr * 64 + m * 16 + (lane & 15);
            af[m] = *(const short8*)&Abuf[ar * 32 + (lane >> 4) * 8];
            int br = wc * 64 + m * 16 + (lane & 15);
            bfr[m] = *(const short8*)&Bbuf[br * 32 + (lane >> 4) * 8];
        }
#pragma unroll
        for (int m = 0; m < 4; ++m)
#pragma unroll
            for (int n = 0; n < 4; ++n)
                acc[m][n] = __builtin_amdgcn_mfma_f32_16x16x32_bf16(af[m], bfr[n], acc[m][n], 0, 0, 0);
        __syncthreads();
    }

#pragma unroll
    for (int n = 0; n < 4; ++n) {
        int cbase = col0 + wc * 64 + n * 16;     // multiple of 16, window within one 64-seg
        int h   = cbase / 192;
        int r3  = cbase % 192;
        int sel = r3 >> 6;                       // 0=q 1=k 2=v, wave-uniform
        int d   = (r3 & 63) + (lane & 15);
        float bv = bias[cbase + (lane & 15)];
#pragma unroll
        for (int m = 0; m < 4; ++m) {
            int rowb = row0 + wr * 64 + m * 16 + (lane >> 4) * 4;
#pragma unroll
            for (int j = 0; j < 4; ++j) {
                int r = rowb + j;
                int s = r >> 1, b = r & 1;       // r = s*B + b, B=2
                size_t off = ((size_t)((b * NH + h) * S + s)) * HD + d;
                float val = acc[m][n][j] + bv;
                if (sel == 0)      Qb[off] = f2bf(val);
                else if (sel == 1) Kb[off] = f2bf(val);
                else               Vf[off] = val;
            }
        }
    }
}

// ---------------------------------------------------------------------------
// V-suffix scan over t per (bh,d) column. 64 chunks of 32 t.
// ---------------------------------------------------------------------------
__global__ void vsuf_chunksum(const float* __restrict__ Vf, float* __restrict__ csum) {
    int idx = blockIdx.x * 256 + threadIdx.x;   // chunk*2048 + col
    int col = idx & 2047;                        // bh*64 + d
    int chunk = idx >> 11;                       // 0..63
    const float* vp = Vf + ((size_t)(col >> 6) * S + chunk * 32) * HD + (col & 63);
    float s = 0.f;
#pragma unroll
    for (int t = 0; t < 32; ++t) s += vp[(size_t)t * HD];
    csum[idx] = s;
}

// Writes Vsuf TRANSPOSED: Vt[bh][d][t] bf16 (t-contiguous for MFMA frags)
__global__ void vsuft_final(const float* __restrict__ Vf, const float* __restrict__ csum,
                            ushort* __restrict__ Vt) {
    int idx = blockIdx.x * 256 + threadIdx.x;
    int col = idx & 2047;
    int chunk = idx >> 11;
    int bh = col >> 6, d = col & 63;
    float acc = 0.f;
    for (int c = chunk + 1; c < 64; ++c) acc += csum[c * 2048 + col];
    const float* vp = Vf + ((size_t)bh * S + chunk * 32) * HD + d;
    ushort buf[32];
#pragma unroll
    for (int tt = 31; tt >= 0; --tt) {
        acc += vp[(size_t)tt * HD];
        buf[tt] = f2bf(acc);
    }
    ushort* op = Vt + ((size_t)bh * HD + d) * S + chunk * 32;
#pragma unroll
    for (int q = 0; q < 4; ++q) {
        short8 o;
#pragma unroll
        for (int k = 0; k < 8; ++k) o[k] = buf[q * 8 + k];
        *(short8*)(op + q * 8) = o;
    }
}

// ---------------------------------------------------------------------------
// K transpose: Kb[bh][t][d] -> Kt[bh][d][t], 64x64 LDS tiles
// ---------------------------------------------------------------------------
__global__ __launch_bounds__(256) void ktrans(const ushort* __restrict__ Kb,
                                              ushort* __restrict__ Kt) {
    __shared__ ushort Ks[64][72];
    const int bh = blockIdx.x;
    const int t0 = blockIdx.y * 64;
    const int tid = threadIdx.x;
    {
        const int tt = tid >> 2, part = (tid & 3) * 16;
        const ushort* src = Kb + ((size_t)bh * S + t0 + tt) * HD + part;
        *(short8*)&Ks[tt][part]     = *(const short8*)(src);
        *(short8*)&Ks[tt][part + 8] = *(const short8*)(src + 8);
    }
    __syncthreads();
    {
        const int d = tid >> 2, tq = (tid & 3) * 16;
        ushort tmp[16];
#pragma unroll
        for (int k = 0; k < 16; ++k) tmp[k] = Ks[tq + k][d];
        ushort* dst = Kt + ((size_t)bh * HD + d) * S + t0 + tq;
        short8 o0, o1;
#pragma unroll
        for (int k = 0; k < 8; ++k) { o0[k] = tmp[k]; o1[k] = tmp[8 + k]; }
        *(short8*)dst = o0;
        *(short8*)(dst + 8) = o1;
    }
}

// ---------------------------------------------------------------------------
// K3: M[i][j] = sum_t Kt[i][t]*Vt[j][t] via MFMA. 16 k-slices of 128 t.
// grid (32 bh, 4), 4 waves -> slice = kb*4+wave. Frags straight from L2.
// ---------------------------------------------------------------------------
__global__ __launch_bounds__(256) void kvm_mfma(const ushort* __restrict__ Kt,
                                                const ushort* __restrict__ Vt,
                                                float* __restrict__ Mpart) {
    const int bh = blockIdx.x, kb = blockIdx.y;
    const int tid = threadIdx.x, wave = tid >> 6, lane = tid & 63;
    const int slice = kb * 4 + wave;
    const ushort* Kp = Kt + (size_t)bh * HD * S;
    const ushort* Vp = Vt + (size_t)bh * HD * S;
    f32x4 acc[4][4] = {};
    const int il = lane & 15;
    const int tbase = slice * 128 + (lane >> 4) * 8;
#pragma unroll
    for (int ks = 0; ks < 4; ++ks) {
        const int t = tbase + ks * 32;
        short8 af[4], bfv[4];
#pragma unroll
        for (int m = 0; m < 4; ++m) af[m]  = *(const short8*)&Kp[(size_t)(m * 16 + il) * S + t];
#pragma unroll
        for (int n = 0; n < 4; ++n) bfv[n] = *(const short8*)&Vp[(size_t)(n * 16 + il) * S + t];
#pragma unroll
        for (int m = 0; m < 4; ++m)
#pragma unroll
            for (int n = 0; n < 4; ++n)
                acc[m][n] = __builtin_amdgcn_mfma_f32_16x16x32_bf16(af[m], bfv[n], acc[m][n], 0, 0, 0);
    }
    float* Mp = Mpart + ((size_t)slice * 32 + bh) * 4096;
#pragma unroll
    for (int m = 0; m < 4; ++m)
#pragma unroll
        for (int n = 0; n < 4; ++n)
#pragma unroll
            for (int j = 0; j < 4; ++j) {
                int i  = m * 16 + (lane >> 4) * 4 + j;
                int jj = n * 16 + il;
                Mp[i * 64 + jj] = acc[m][n][j];
            }
}

// ---------------------------------------------------------------------------
// K4: out[s][b][h*64+d] = scale * sum_i q[s][i]*M[i][d] via MFMA.
// Folds the Mpart reduce (16 slices) + LDS transpose of M. grid (32 bh, 8).
// ---------------------------------------------------------------------------
__global__ __launch_bounds__(256) void qm_mfma(const ushort* __restrict__ Qb,
                                               const float* __restrict__ Mpart,
                                               float* __restrict__ out) {
    __shared__ ushort Mt[64][72];   // Mt[d][i] = M[i][d], bf16
    const int bh = blockIdx.x, b = bh >> 4, h = bh & 15;
    const int tid = threadIdx.x;
    {
        const int i = tid >> 2, jq = (tid & 3) * 16;
        f32x4 s0 = {}, s1 = {}, s2 = {}, s3 = {};
#pragma unroll
        for (int sl = 0; sl < 16; ++sl) {
            const float* p = Mpart + ((size_t)sl * 32 + bh) * 4096 + i * 64 + jq;
            s0 += *(const f32x4*)(p);
            s1 += *(const f32x4*)(p + 4);
            s2 += *(const f32x4*)(p + 8);
            s3 += *(const f32x4*)(p + 12);
        }
#pragma unroll
        for (int k = 0; k < 4; ++k) {
            Mt[jq + 0  + k][i] = f2bf(s0[k]);
            Mt[jq + 4  + k][i] = f2bf(s1[k]);
            Mt[jq + 8  + k][i] = f2bf(s2[k]);
            Mt[jq + 12 + k][i] = f2bf(s3[k]);
        }
    }
    __syncthreads();
    const int wave = tid >> 6, lane = tid & 63;
    const int sl15 = lane & 15, koct = (lane >> 4) * 8;
    const int s0b = blockIdx.y * 256 + wave * 64;
    f32x4 acc[4][4] = {};
#pragma unroll
    for (int ks = 0; ks < 2; ++ks) {
        short8 af[4], bfv[4];
#pragma unroll
        for (int m = 0; m < 4; ++m) {
            int s = s0b + m * 16 + sl15;
            af[m] = *(const short8*)&Qb[((size_t)bh * S + s) * HD + ks * 32 + koct];
        }
#pragma unroll
        for (int n = 0; n < 4; ++n)
            bfv[n] = *(const short8*)&Mt[n * 16 + sl15][ks * 32 + koct];
#pragma unroll
        for (int m = 0; m < 4; ++m)
#pragma unroll
            for (int n = 0; n < 4; ++n)
                acc[m][n] = __builtin_amdgcn_mfma_f32_16x16x32_bf16(af[m], bfv[n], acc[m][n], 0, 0, 0);
    }
    const float scale = 0.125f * 0.02209708691207961f;  // HD^-0.5 * S^-0.5
#pragma unroll
    for (int m = 0; m < 4; ++m)
#pragma unroll
        for (int n = 0; n < 4; ++n)
#pragma unroll
            for (int j = 0; j < 4; ++j) {
                int s = s0b + m * 16 + (lane >> 4) * 4 + j;
                int d = n * 16 + sl15;
                out[(size_t)(s * B + b) * H + h * 64 + d] = acc[m][n][j] * scale;
            }
}

// ---------------------------------------------------------------------------
extern "C" void kernel_launch(void* const* d_in, const int* in_sizes, int n_in,
                              void* d_out, int out_size, void* d_ws, size_t ws_size,
                              hipStream_t stream) {
    const float* hidden = (const float*)d_in[0];
    const float* W      = (const float*)d_in[1];
    const float* bias   = (const float*)d_in[2];
    float* out = (float*)d_out;

    float*  Vf    = (float*)d_ws;                       // 16 MB  [bh][t][d] f32
    ushort* Qb    = (ushort*)(Vf + 4194304);            //  8 MB  [bh][s][d] bf16
    ushort* Kb    = Qb + 4194304;                       //  8 MB  [bh][t][d] bf16
    ushort* Kt    = Kb + 4194304;                       //  8 MB  [bh][d][t] bf16
    ushort* Vt    = Kt + 4194304;                       //  8 MB  [bh][d][t] bf16
    float*  csum  = (float*)(Vt + 4194304);             // 0.5 MB [chunk][col]
    float*  Mpart = csum + 131072;                      //  8 MB  [16][bh][64][64]
    ushort* Abf   = (ushort*)(Mpart + 2097152);         //  8 MB
    ushort* Wbf   = Abf + 4194304;                      //  6 MB
    // total ~70.5 MB of d_ws

    cast_both<<<(N8_A + N8_W + 255) / 256, 256, 0, stream>>>(hidden, W, Abf, Wbf);
    qkv_gemm_mfma<<<dim3(ROWS / 128, THREE_H / 128), 256, 0, stream>>>(Abf, Wbf, bias, Qb, Kb, Vf);
    vsuf_chunksum<<<512, 256, 0, stream>>>(Vf, csum);
    vsuft_final<<<512, 256, 0, stream>>>(Vf, csum, Vt);
    ktrans<<<dim3(32, 32), 256, 0, stream>>>(Kb, Kt);
    kvm_mfma<<<dim3(32, 4), 256, 0, stream>>>(Kt, Vt, Mpart);
    qm_mfma<<<dim3(32, 8), 256, 0, stream>>>(Qb, Mpart, out);
}